// Round 6
// baseline (451.107 us; speedup 1.0000x reference)
//
#include <hip/hip_runtime.h>
#include <hip/hip_cooperative_groups.h>
#include <stdint.h>

namespace cg = cooperative_groups;

#define BN_EPS 1e-3f

// ============================================================
// Weight prep helpers (shared by fused + fallback paths)
//  - w1s[864]: sign floats, w1s[tap*32+c] = (w1<0 ? -1.f : 1.f)
//  - w2p/w3p/w4p: bit-packed signs, bit=1 <=> w<0, layout [(tap*CINW+wi)][COUT]
// ============================================================
template <int CIN, int COUT>
__device__ inline void packw(const float* __restrict__ w, uint32_t* __restrict__ wp, int idx) {
    const int CINW = CIN / 32;
    int co = idx % COUT;
    int t2 = idx / COUT;
    int wi = t2 % CINW;
    int tap = t2 / CINW;
    uint32_t word = 0;
#pragma unroll
    for (int bb = 0; bb < 32; bb++) {
        float val = w[((tap * CIN) + wi * 32 + bb) * COUT + co];
        word |= (uint32_t)(val < 0.f) << bb;
    }
    wp[idx] = word;
}

struct FusedParams {
    const float *x, *w1, *m1, *v1, *b1;
    const float *w2, *m2, *v2, *b2;
    const float *w3, *m3, *v3, *b3;
    const float *w4, *m4, *v4, *b4;
    float* out;
    uint32_t* y1p;
    uint2* y2p;
    uint32_t* y3p;
    float* w1s;
    uint32_t *w2p, *w3p, *w4p;
};

// ============================================================
// FUSED whole-network kernel (cooperative). One dispatch replaces 5.
// Phase bodies are verbatim copies of absmax-0.0-verified kernels
// (R1 conv1; R5 bconv2/3/4) with only per-lane-invariant weight/BN
// loads hoisted out of the block-stride loops (numerically identical).
// LDS: one 14.2 KB buffer aliased by all phases.
// __launch_bounds__(256,4) -> VGPR<=128, so <=4 blocks/CU co-resident.
// ============================================================
__global__ __launch_bounds__(256, 4) void fused_all(FusedParams P) {
    __shared__ __align__(16) float smem[34 * 104];   // 14144 B, aliased below
    cg::grid_group grid = cg::this_grid();
    const int tid = threadIdx.x;
    const int nblk = gridDim.x;

    // -------- Phase 0: weight pack --------
    {
        int idx = blockIdx.x * 256 + tid;
        if (idx < 864) {
            P.w1s[idx] = (P.w1[idx] < 0.f) ? -1.f : 1.f;
        } else {
            idx -= 864;
            if (idx < 576) { packw<32, 64>(P.w2, P.w2p, idx); }
            else {
                idx -= 576;
                if (idx < 2304) { packw<64, 128>(P.w3, P.w3p, idx); }
                else {
                    idx -= 2304;
                    if (idx < 9216) { packw<128, 256>(P.w4, P.w4p, idx); }
                }
            }
        }
    }
    grid.sync();

    // -------- Phase 1: conv1 + pool + bn + sign -> y1p --------
    {
        int wave = tid >> 6, lane = tid & 63;
        int px = lane & 15, py = (wave << 2) + (lane >> 4);
        for (int tile = blockIdx.x; tile < 1024; tile += nblk) {
            int tx = tile & 3;
            int ty = (tile >> 2) & 3;
            int n  = tile >> 4;
            int ph0 = ty * 16, pw0 = tx * 16;
            int r0 = 2 * ph0;
            int cf0 = pw0 * 6;

            for (int i = tid; i < 34 * 102; i += 256) {
                int r = i / 102, c = i % 102;
                int gr = r0 + r, gcf = cf0 + c;
                float vv = 0.f;
                if (gr < 128 && gcf < 384)
                    vv = P.x[(size_t)(n * 128 + gr) * 384 + gcf];
                smem[r * 104 + c] = vv;
            }
            __syncthreads();

            int ph = ph0 + py, pw = pw0 + px;

            float win[48];
#pragma unroll
            for (int r = 0; r < 4; r++) {
                const float2* bp = (const float2*)&smem[(2 * py + r) * 104 + 6 * px];
#pragma unroll
                for (int q = 0; q < 6; q++) {
                    float2 f2 = bp[q];
                    win[r * 12 + 2 * q]     = f2.x;
                    win[r * 12 + 2 * q + 1] = f2.y;
                }
            }

            uint32_t word = 0;
#pragma unroll 1
            for (int g = 0; g < 4; g++) {              // 8 channels per group
                float acc[8][4];
#pragma unroll
                for (int j = 0; j < 8; j++)
#pragma unroll
                    for (int p = 0; p < 4; p++) acc[j][p] = 0.f;

                const float* sgc = P.w1s + g * 8;      // wave-uniform base
#pragma unroll
                for (int kh = 0; kh < 3; kh++)
#pragma unroll
                    for (int kw = 0; kw < 3; kw++)
#pragma unroll
                        for (int ci = 0; ci < 3; ci++) {
                            int tap = (kh * 3 + kw) * 3 + ci;
                            float x00 = win[kh * 12 + kw * 3 + ci];
                            float x01 = win[kh * 12 + (kw + 1) * 3 + ci];
                            float x10 = win[(kh + 1) * 12 + kw * 3 + ci];
                            float x11 = win[(kh + 1) * 12 + (kw + 1) * 3 + ci];
                            float4 s0 = *(const float4*)(sgc + tap * 32);
                            float4 s1 = *(const float4*)(sgc + tap * 32 + 4);
                            float sv[8] = {s0.x, s0.y, s0.z, s0.w, s1.x, s1.y, s1.z, s1.w};
#pragma unroll
                            for (int j = 0; j < 8; j++) {
                                acc[j][0] += x00 * sv[j];
                                acc[j][1] += x01 * sv[j];
                                acc[j][2] += x10 * sv[j];
                                acc[j][3] += x11 * sv[j];
                            }
                        }
#pragma unroll
                for (int j = 0; j < 8; j++) {
                    float mx = fmaxf(fmaxf(acc[j][0], acc[j][1]), fmaxf(acc[j][2], acc[j][3]));
                    int ch = g * 8 + j;
                    float y = (mx - P.m1[ch]) * rsqrtf(P.v1[ch] + BN_EPS) + P.b1[ch];
                    word |= (uint32_t)(y < 0.f) << ch;
                }
            }

            if (ph < 63 && pw < 63)
                P.y1p[(n * 63 + ph) * 63 + pw] = word;
            __syncthreads();                           // protect smem for next tile
        }
    }
    grid.sync();

    // -------- Phase 2: bconv2 + pool + bn + sign -> y2p --------
    {
        uint32_t* tl = (uint32_t*)smem;                // 4 rows x 63 words (pad 64)
        int lane = tid & 63;
        int wave = __builtin_amdgcn_readfirstlane(tid >> 6);

        uint32_t wq[9];
#pragma unroll
        for (int tap = 0; tap < 9; tap++) wq[tap] = P.w2p[tap * 64 + lane];
        float mm = P.m2[lane];
        float rs = rsqrtf(P.v2[lane] + BN_EPS);
        float bb = P.b2[lane];

        for (int blk = blockIdx.x; blk < 64 * 31; blk += nblk) {
            int ph = blk % 31;
            int n  = blk / 31;
            int row0 = 2 * ph - 1;
            for (int i = tid; i < 4 * 63; i += 256) {
                int r = i / 63, c = i % 63;
                int rr = min(max(row0 + r, 0), 62);
                tl[r * 64 + c] = P.y1p[(n * 63 + rr) * 63 + c];
            }
            __syncthreads();

            for (int it = 0; it < 2; it++) {
                int pwg = wave * 2 + it;               // 0..7
                uint2 res[4];

                if (ph > 0 && pwg > 0) {
                    int col0 = 8 * pwg - 1;
                    uint32_t win[4][10];
#pragma unroll
                    for (int r = 0; r < 4; r++)
#pragma unroll
                        for (int c = 0; c < 10; c++)
                            win[r][c] = tl[r * 64 + min(col0 + c, 62)];

#pragma unroll
                    for (int p = 0; p < 4; p++) {
                        int a0 = 0, a1 = 0, a2 = 0, a3 = 0;
#pragma unroll
                        for (int kh = 0; kh < 3; kh++)
#pragma unroll
                            for (int kw = 0; kw < 3; kw++) {
                                uint32_t w = wq[kh * 3 + kw];
                                a0 += __popc(win[kh][2 * p + kw] ^ w);
                                a1 += __popc(win[kh][2 * p + kw + 1] ^ w);
                                a2 += __popc(win[kh + 1][2 * p + kw] ^ w);
                                a3 += __popc(win[kh + 1][2 * p + kw + 1] ^ w);
                            }
                        int mn = min(min(a0, a1), min(a2, a3));
                        int best = 288 - 2 * mn;
                        float y = ((float)best - mm) * rs + bb;
                        unsigned long long bal = __ballot(y < 0.f);
                        res[p] = make_uint2((uint32_t)bal, (uint32_t)(bal >> 32));
                    }
                } else {
#pragma unroll
                    for (int p = 0; p < 4; p++) {
                        int pw = 4 * pwg + p;
                        int best = -1000000;
                        if (pw < 31) {
#pragma unroll
                            for (int dy = 0; dy < 2; dy++)
#pragma unroll
                                for (int dx = 0; dx < 2; dx++) {
                                    int oh = 2 * ph + dy, ow = 2 * pw + dx;
                                    int acc = 0, K = 0;
#pragma unroll
                                    for (int kh = 0; kh < 3; kh++) {
                                        int ih = oh - 1 + kh;
                                        bool rok = (ih >= 0) && (ih < 63);
#pragma unroll
                                        for (int kw = 0; kw < 3; kw++) {
                                            int iw = ow - 1 + kw;
                                            bool ok = rok && (iw >= 0) && (iw < 63);
                                            uint32_t wv = tl[(dy + kh) * 64 + min(max(iw, 0), 62)];
                                            if (ok) { acc += __popc(wv ^ wq[kh * 3 + kw]); K += 32; }
                                        }
                                    }
                                    best = max(best, K - 2 * acc);
                                }
                        }
                        float y = ((float)best - mm) * rs + bb;
                        unsigned long long bal = __ballot(y < 0.f);
                        res[p] = make_uint2((uint32_t)bal, (uint32_t)(bal >> 32));
                    }
                }

                uint2 rr = res[0];
                if (lane == 1) rr = res[1];
                if (lane == 2) rr = res[2];
                if (lane == 3) rr = res[3];
                int pws = 4 * pwg + lane;
                if (lane < 4 && pws < 31)
                    P.y2p[(n * 31 + ph) * 31 + pws] = rr;
            }
            __syncthreads();                           // before next stage
        }
    }
    grid.sync();

    // -------- Phase 3: bconv3 + pool + bn + sign -> y3p --------
    {
        uint2* tl = (uint2*)smem;                      // 4 rows x 31 uint2 (pad 32)
        int lane = tid & 63;
        int wave = __builtin_amdgcn_readfirstlane(tid >> 6);
        int half = wave & 1;
        int co = half * 64 + lane;

        uint32_t wq0[9], wq1[9];
#pragma unroll
        for (int tap = 0; tap < 9; tap++) {
            wq0[tap] = P.w3p[(tap * 2 + 0) * 128 + co];
            wq1[tap] = P.w3p[(tap * 2 + 1) * 128 + co];
        }
        float mm = P.m3[co];
        float rs = rsqrtf(P.v3[co] + BN_EPS);
        float bb = P.b3[co];

        for (int blk = blockIdx.x; blk < 64 * 15; blk += nblk) {
            int ph = blk % 15;
            int n  = blk / 15;
            int row0 = 2 * ph - 1;
            for (int i = tid; i < 4 * 31; i += 256) {
                int r = i / 31, c = i % 31;
                int rr = min(max(row0 + r, 0), 30);
                tl[r * 32 + c] = P.y2p[(n * 31 + rr) * 31 + c];
            }
            __syncthreads();

            for (int it = 0; it < 4; it++) {
                int pwg = (wave >> 1) * 4 + it;        // 0..7
                unsigned long long bal0, bal1;

                if (ph > 0 && pwg > 0) {
                    int col0 = 4 * pwg - 1;
                    uint2 win[4][6];
#pragma unroll
                    for (int r = 0; r < 4; r++)
#pragma unroll
                        for (int c = 0; c < 6; c++)
                            win[r][c] = tl[r * 32 + min(col0 + c, 30)];

                    unsigned long long bals[2];
#pragma unroll
                    for (int p = 0; p < 2; p++) {
                        int a0 = 0, a1 = 0, a2 = 0, a3 = 0;
#pragma unroll
                        for (int kh = 0; kh < 3; kh++)
#pragma unroll
                            for (int kw = 0; kw < 3; kw++) {
                                int tap = kh * 3 + kw;
                                uint32_t u0 = wq0[tap], u1 = wq1[tap];
                                a0 += __popc(win[kh][2 * p + kw].x ^ u0) + __popc(win[kh][2 * p + kw].y ^ u1);
                                a1 += __popc(win[kh][2 * p + kw + 1].x ^ u0) + __popc(win[kh][2 * p + kw + 1].y ^ u1);
                                a2 += __popc(win[kh + 1][2 * p + kw].x ^ u0) + __popc(win[kh + 1][2 * p + kw].y ^ u1);
                                a3 += __popc(win[kh + 1][2 * p + kw + 1].x ^ u0) + __popc(win[kh + 1][2 * p + kw + 1].y ^ u1);
                            }
                        int mn = min(min(a0, a1), min(a2, a3));
                        int best = 576 - 2 * mn;
                        float y = ((float)best - mm) * rs + bb;
                        bals[p] = __ballot(y < 0.f);
                    }
                    bal0 = bals[0]; bal1 = bals[1];
                } else {
                    unsigned long long bals[2];
#pragma unroll
                    for (int p = 0; p < 2; p++) {
                        int pw = 2 * pwg + p;
                        int best = -1000000;
                        if (pw < 15) {
#pragma unroll
                            for (int dy = 0; dy < 2; dy++)
#pragma unroll
                                for (int dx = 0; dx < 2; dx++) {
                                    int oh = 2 * ph + dy, ow = 2 * pw + dx;
                                    int acc = 0, K = 0;
#pragma unroll
                                    for (int kh = 0; kh < 3; kh++) {
                                        int ih = oh - 1 + kh;
                                        bool rok = (ih >= 0) && (ih < 31);
#pragma unroll
                                        for (int kw = 0; kw < 3; kw++) {
                                            int iw = ow - 1 + kw;
                                            bool ok = rok && (iw >= 0) && (iw < 31);
                                            uint2 iv = tl[(dy + kh) * 32 + min(max(iw, 0), 30)];
                                            int tap = kh * 3 + kw;
                                            if (ok) {
                                                acc += __popc(iv.x ^ wq0[tap]) + __popc(iv.y ^ wq1[tap]);
                                                K += 64;
                                            }
                                        }
                                    }
                                    best = max(best, K - 2 * acc);
                                }
                        }
                        float y = ((float)best - mm) * rs + bb;
                        bals[p] = __ballot(y < 0.f);
                    }
                    bal0 = bals[0]; bal1 = bals[1];
                }

                uint32_t val = (uint32_t)bal0;
                if (lane == 1) val = (uint32_t)(bal0 >> 32);
                if (lane == 2) val = (uint32_t)bal1;
                if (lane == 3) val = (uint32_t)(bal1 >> 32);
                int p = lane >> 1;
                int pw = 2 * pwg + p;
                if (lane < 4 && pw < 15) {
                    int pixel = (n * 15 + ph) * 15 + pw;
                    P.y3p[pixel * 4 + half * 2 + (lane & 1)] = val;
                }
            }
            __syncthreads();                           // before next stage
        }
    }
    grid.sync();

    // -------- Phase 4: bconv4 + pool + bn -> out (f32) --------
    {
        uint32_t* tl = (uint32_t*)smem;                // 4x4 window of uint4
        const uint4* tp = (const uint4*)tl;
        int lane = tid & 63;
        int co = (tid >> 6) * 64 + lane;

        uint4 wq[9];
#pragma unroll
        for (int tap = 0; tap < 9; tap++) {
            wq[tap].x = P.w4p[(tap * 4 + 0) * 256 + co];
            wq[tap].y = P.w4p[(tap * 4 + 1) * 256 + co];
            wq[tap].z = P.w4p[(tap * 4 + 2) * 256 + co];
            wq[tap].w = P.w4p[(tap * 4 + 3) * 256 + co];
        }
        float mm = P.m4[co];
        float rs = rsqrtf(P.v4[co] + BN_EPS);
        float bbv = P.b4[co];

        for (int pixel = blockIdx.x; pixel < 64 * 7 * 7; pixel += nblk) {
            int pw = pixel % 7;
            int t = pixel / 7;
            int ph = t % 7;
            int n = t / 7;

            if (tid < 64) {
                int tt = tid;
                int r = tt >> 4, e = (tt >> 2) & 3, w = tt & 3;
                int gr = 2 * ph - 1 + r, gc = 2 * pw - 1 + e;
                uint32_t val = 0;
                if (gr >= 0 && gr < 15 && gc >= 0 && gc < 15)
                    val = P.y3p[(((size_t)(n * 15 + gr) * 15 + gc) << 2) + w];
                tl[tt] = val;
            }
            __syncthreads();

            int best;
            if (ph > 0 && pw > 0) {
                int a0 = 0, a1 = 0, a2 = 0, a3 = 0;
#pragma unroll
                for (int r = 0; r < 4; r++)
#pragma unroll
                    for (int c = 0; c < 4; c++) {
                        uint4 iv = tp[r * 4 + c];
#pragma unroll
                        for (int kh = 0; kh < 3; kh++) {
                            int dy = r - kh;
                            if (dy < 0 || dy > 1) continue;
#pragma unroll
                            for (int kw = 0; kw < 3; kw++) {
                                int dx = c - kw;
                                if (dx < 0 || dx > 1) continue;
                                int tap = kh * 3 + kw;
                                int pc = __popc(iv.x ^ wq[tap].x) + __popc(iv.y ^ wq[tap].y)
                                       + __popc(iv.z ^ wq[tap].z) + __popc(iv.w ^ wq[tap].w);
                                if (dy == 0 && dx == 0) a0 += pc;
                                else if (dy == 0) a1 += pc;
                                else if (dx == 0) a2 += pc;
                                else a3 += pc;
                            }
                        }
                    }
                best = max(max(1152 - 2 * a0, 1152 - 2 * a1), max(1152 - 2 * a2, 1152 - 2 * a3));
            } else {
                best = -1000000;
#pragma unroll
                for (int dy = 0; dy < 2; dy++)
#pragma unroll
                    for (int dx = 0; dx < 2; dx++) {
                        int oh = 2 * ph + dy, ow = 2 * pw + dx;
                        int acc = 0, K = 0;
#pragma unroll
                        for (int kh = 0; kh < 3; kh++) {
                            int ih = oh - 1 + kh;
                            if (ih < 0 || ih >= 15) continue;
#pragma unroll
                            for (int kw = 0; kw < 3; kw++) {
                                int iw = ow - 1 + kw;
                                if (iw < 0 || iw >= 15) continue;
                                uint4 iv = tp[(dy + kh) * 4 + (dx + kw)];
                                int tap = kh * 3 + kw;
                                acc += __popc(iv.x ^ wq[tap].x) + __popc(iv.y ^ wq[tap].y)
                                     + __popc(iv.z ^ wq[tap].z) + __popc(iv.w ^ wq[tap].w);
                                K += 128;
                            }
                        }
                        best = max(best, K - 2 * acc);
                    }
            }
            float y = ((float)best - mm) * rs + bbv;
            P.out[pixel * 256 + co] = y;
            __syncthreads();                           // before next stage
        }
    }
}

// ============================================================
// FALLBACK path: the verified 5-kernel pipeline (R5, absmax 0.0).
// Used only if the cooperative launch is rejected.
// ============================================================
__global__ void pack_all(const float* __restrict__ w1, const float* __restrict__ w2,
                         const float* __restrict__ w3, const float* __restrict__ w4,
                         float* __restrict__ w1s, uint32_t* __restrict__ w2p,
                         uint32_t* __restrict__ w3p, uint32_t* __restrict__ w4p) {
    int idx = blockIdx.x * 256 + threadIdx.x;
    if (idx < 864) {
        w1s[idx] = (w1[idx] < 0.f) ? -1.f : 1.f;
        return;
    }
    idx -= 864;
    if (idx < 576) { packw<32, 64>(w2, w2p, idx); return; }
    idx -= 576;
    if (idx < 2304) { packw<64, 128>(w3, w3p, idx); return; }
    idx -= 2304;
    if (idx < 9216) { packw<128, 256>(w4, w4p, idx); return; }
}

__global__ __launch_bounds__(256, 4) void conv1_k(const float* __restrict__ x,
                                                  const float* __restrict__ w1s,
                                                  const float* __restrict__ m1,
                                                  const float* __restrict__ v1,
                                                  const float* __restrict__ b1,
                                                  uint32_t* __restrict__ y1p) {
    __shared__ __align__(16) float xt[34 * 104];

    int tile = blockIdx.x;
    int tx = tile & 3;
    int ty = (tile >> 2) & 3;
    int n  = tile >> 4;
    int ph0 = ty * 16, pw0 = tx * 16;
    int r0 = 2 * ph0;
    int cf0 = pw0 * 6;

    for (int i = threadIdx.x; i < 34 * 102; i += 256) {
        int r = i / 102, c = i % 102;
        int gr = r0 + r, gcf = cf0 + c;
        float vv = 0.f;
        if (gr < 128 && gcf < 384)
            vv = x[(size_t)(n * 128 + gr) * 384 + gcf];
        xt[r * 104 + c] = vv;
    }
    __syncthreads();

    int wave = threadIdx.x >> 6, lane = threadIdx.x & 63;
    int px = lane & 15, py = (wave << 2) + (lane >> 4);
    int ph = ph0 + py, pw = pw0 + px;

    float win[48];
#pragma unroll
    for (int r = 0; r < 4; r++) {
        const float2* bp = (const float2*)&xt[(2 * py + r) * 104 + 6 * px];
#pragma unroll
        for (int q = 0; q < 6; q++) {
            float2 f2 = bp[q];
            win[r * 12 + 2 * q]     = f2.x;
            win[r * 12 + 2 * q + 1] = f2.y;
        }
    }

    uint32_t word = 0;
#pragma unroll 1
    for (int g = 0; g < 4; g++) {
        float acc[8][4];
#pragma unroll
        for (int j = 0; j < 8; j++)
#pragma unroll
            for (int p = 0; p < 4; p++) acc[j][p] = 0.f;

        const float* sgc = w1s + g * 8;
#pragma unroll
        for (int kh = 0; kh < 3; kh++)
#pragma unroll
            for (int kw = 0; kw < 3; kw++)
#pragma unroll
                for (int ci = 0; ci < 3; ci++) {
                    int tap = (kh * 3 + kw) * 3 + ci;
                    float x00 = win[kh * 12 + kw * 3 + ci];
                    float x01 = win[kh * 12 + (kw + 1) * 3 + ci];
                    float x10 = win[(kh + 1) * 12 + kw * 3 + ci];
                    float x11 = win[(kh + 1) * 12 + (kw + 1) * 3 + ci];
                    float4 s0 = *(const float4*)(sgc + tap * 32);
                    float4 s1 = *(const float4*)(sgc + tap * 32 + 4);
                    float sv[8] = {s0.x, s0.y, s0.z, s0.w, s1.x, s1.y, s1.z, s1.w};
#pragma unroll
                    for (int j = 0; j < 8; j++) {
                        acc[j][0] += x00 * sv[j];
                        acc[j][1] += x01 * sv[j];
                        acc[j][2] += x10 * sv[j];
                        acc[j][3] += x11 * sv[j];
                    }
                }
#pragma unroll
        for (int j = 0; j < 8; j++) {
            float mx = fmaxf(fmaxf(acc[j][0], acc[j][1]), fmaxf(acc[j][2], acc[j][3]));
            int ch = g * 8 + j;
            float y = (mx - m1[ch]) * rsqrtf(v1[ch] + BN_EPS) + b1[ch];
            word |= (uint32_t)(y < 0.f) << ch;
        }
    }

    if (ph < 63 && pw < 63)
        y1p[(n * 63 + ph) * 63 + pw] = word;
}

__global__ __launch_bounds__(256, 2) void bconv2(const uint32_t* __restrict__ y1p,
                                                 const uint32_t* __restrict__ w2p,
                                                 const float* __restrict__ m,
                                                 const float* __restrict__ v,
                                                 const float* __restrict__ b,
                                                 uint2* __restrict__ y2p) {
    __shared__ uint32_t tile[4 * 64];

    int blk = blockIdx.x;
    int ph = blk % 31;
    int n  = blk / 31;
    int lane = threadIdx.x & 63;
    int wave = __builtin_amdgcn_readfirstlane(threadIdx.x >> 6);

    int row0 = 2 * ph - 1;
    for (int i = threadIdx.x; i < 4 * 63; i += 256) {
        int r = i / 63, c = i % 63;
        int rr = min(max(row0 + r, 0), 62);
        tile[r * 64 + c] = y1p[(n * 63 + rr) * 63 + c];
    }
    __syncthreads();

    uint32_t wq[9];
#pragma unroll
    for (int tap = 0; tap < 9; tap++) wq[tap] = w2p[tap * 64 + lane];
    float mm = m[lane], vv = v[lane], bb = b[lane];
    float rs = rsqrtf(vv + BN_EPS);

    for (int it = 0; it < 2; it++) {
        int pwg = wave * 2 + it;
        uint2 res[4];

        if (ph > 0 && pwg > 0) {
            int col0 = 8 * pwg - 1;
            uint32_t win[4][10];
#pragma unroll
            for (int r = 0; r < 4; r++)
#pragma unroll
                for (int c = 0; c < 10; c++)
                    win[r][c] = tile[r * 64 + min(col0 + c, 62)];

#pragma unroll
            for (int p = 0; p < 4; p++) {
                int a0 = 0, a1 = 0, a2 = 0, a3 = 0;
#pragma unroll
                for (int kh = 0; kh < 3; kh++)
#pragma unroll
                    for (int kw = 0; kw < 3; kw++) {
                        uint32_t w = wq[kh * 3 + kw];
                        a0 += __popc(win[kh][2 * p + kw] ^ w);
                        a1 += __popc(win[kh][2 * p + kw + 1] ^ w);
                        a2 += __popc(win[kh + 1][2 * p + kw] ^ w);
                        a3 += __popc(win[kh + 1][2 * p + kw + 1] ^ w);
                    }
                int mn = min(min(a0, a1), min(a2, a3));
                int best = 288 - 2 * mn;
                float y = ((float)best - mm) * rs + bb;
                unsigned long long bal = __ballot(y < 0.f);
                res[p] = make_uint2((uint32_t)bal, (uint32_t)(bal >> 32));
            }
        } else {
#pragma unroll
            for (int p = 0; p < 4; p++) {
                int pw = 4 * pwg + p;
                int best = -1000000;
                if (pw < 31) {
#pragma unroll
                    for (int dy = 0; dy < 2; dy++)
#pragma unroll
                        for (int dx = 0; dx < 2; dx++) {
                            int oh = 2 * ph + dy, ow = 2 * pw + dx;
                            int acc = 0, K = 0;
#pragma unroll
                            for (int kh = 0; kh < 3; kh++) {
                                int ih = oh - 1 + kh;
                                bool rok = (ih >= 0) && (ih < 63);
#pragma unroll
                                for (int kw = 0; kw < 3; kw++) {
                                    int iw = ow - 1 + kw;
                                    bool ok = rok && (iw >= 0) && (iw < 63);
                                    uint32_t wv = tile[(dy + kh) * 64 + min(max(iw, 0), 62)];
                                    if (ok) { acc += __popc(wv ^ wq[kh * 3 + kw]); K += 32; }
                                }
                            }
                            best = max(best, K - 2 * acc);
                        }
                }
                float y = ((float)best - mm) * rs + bb;
                unsigned long long bal = __ballot(y < 0.f);
                res[p] = make_uint2((uint32_t)bal, (uint32_t)(bal >> 32));
            }
        }

        uint2 rr = res[0];
        if (lane == 1) rr = res[1];
        if (lane == 2) rr = res[2];
        if (lane == 3) rr = res[3];
        int pws = 4 * pwg + lane;
        if (lane < 4 && pws < 31)
            y2p[(n * 31 + ph) * 31 + pws] = rr;
    }
}

__global__ __launch_bounds__(256, 2) void bconv3(const uint2* __restrict__ y2p,
                                                 const uint32_t* __restrict__ w3p,
                                                 const float* __restrict__ m,
                                                 const float* __restrict__ v,
                                                 const float* __restrict__ b,
                                                 uint32_t* __restrict__ y3p) {
    __shared__ uint2 tile[4 * 32];

    int blk = blockIdx.x;
    int ph = blk % 15;
    int n  = blk / 15;
    int lane = threadIdx.x & 63;
    int wave = __builtin_amdgcn_readfirstlane(threadIdx.x >> 6);
    int half = wave & 1;
    int co = half * 64 + lane;

    int row0 = 2 * ph - 1;
    for (int i = threadIdx.x; i < 4 * 31; i += 256) {
        int r = i / 31, c = i % 31;
        int rr = min(max(row0 + r, 0), 30);
        tile[r * 32 + c] = y2p[(n * 31 + rr) * 31 + c];
    }
    __syncthreads();

    uint32_t wq0[9], wq1[9];
#pragma unroll
    for (int tap = 0; tap < 9; tap++) {
        wq0[tap] = w3p[(tap * 2 + 0) * 128 + co];
        wq1[tap] = w3p[(tap * 2 + 1) * 128 + co];
    }
    float mm = m[co], vv = v[co], bb = b[co];
    float rs = rsqrtf(vv + BN_EPS);

    for (int it = 0; it < 4; it++) {
        int pwg = (wave >> 1) * 4 + it;
        unsigned long long bal0, bal1;

        if (ph > 0 && pwg > 0) {
            int col0 = 4 * pwg - 1;
            uint2 win[4][6];
#pragma unroll
            for (int r = 0; r < 4; r++)
#pragma unroll
                for (int c = 0; c < 6; c++)
                    win[r][c] = tile[r * 32 + min(col0 + c, 30)];

            unsigned long long bals[2];
#pragma unroll
            for (int p = 0; p < 2; p++) {
                int a0 = 0, a1 = 0, a2 = 0, a3 = 0;
#pragma unroll
                for (int kh = 0; kh < 3; kh++)
#pragma unroll
                    for (int kw = 0; kw < 3; kw++) {
                        int tap = kh * 3 + kw;
                        uint32_t u0 = wq0[tap], u1 = wq1[tap];
                        a0 += __popc(win[kh][2 * p + kw].x ^ u0) + __popc(win[kh][2 * p + kw].y ^ u1);
                        a1 += __popc(win[kh][2 * p + kw + 1].x ^ u0) + __popc(win[kh][2 * p + kw + 1].y ^ u1);
                        a2 += __popc(win[kh + 1][2 * p + kw].x ^ u0) + __popc(win[kh + 1][2 * p + kw].y ^ u1);
                        a3 += __popc(win[kh + 1][2 * p + kw + 1].x ^ u0) + __popc(win[kh + 1][2 * p + kw + 1].y ^ u1);
                    }
                int mn = min(min(a0, a1), min(a2, a3));
                int best = 576 - 2 * mn;
                float y = ((float)best - mm) * rs + bb;
                bals[p] = __ballot(y < 0.f);
            }
            bal0 = bals[0]; bal1 = bals[1];
        } else {
            unsigned long long bals[2];
#pragma unroll
            for (int p = 0; p < 2; p++) {
                int pw = 2 * pwg + p;
                int best = -1000000;
                if (pw < 15) {
#pragma unroll
                    for (int dy = 0; dy < 2; dy++)
#pragma unroll
                        for (int dx = 0; dx < 2; dx++) {
                            int oh = 2 * ph + dy, ow = 2 * pw + dx;
                            int acc = 0, K = 0;
#pragma unroll
                            for (int kh = 0; kh < 3; kh++) {
                                int ih = oh - 1 + kh;
                                bool rok = (ih >= 0) && (ih < 31);
#pragma unroll
                                for (int kw = 0; kw < 3; kw++) {
                                    int iw = ow - 1 + kw;
                                    bool ok = rok && (iw >= 0) && (iw < 31);
                                    uint2 iv = tile[(dy + kh) * 32 + min(max(iw, 0), 30)];
                                    int tap = kh * 3 + kw;
                                    if (ok) {
                                        acc += __popc(iv.x ^ wq0[tap]) + __popc(iv.y ^ wq1[tap]);
                                        K += 64;
                                    }
                                }
                            }
                            best = max(best, K - 2 * acc);
                        }
                }
                float y = ((float)best - mm) * rs + bb;
                bals[p] = __ballot(y < 0.f);
            }
            bal0 = bals[0]; bal1 = bals[1];
        }

        uint32_t val = (uint32_t)bal0;
        if (lane == 1) val = (uint32_t)(bal0 >> 32);
        if (lane == 2) val = (uint32_t)bal1;
        if (lane == 3) val = (uint32_t)(bal1 >> 32);
        int p = lane >> 1;
        int pw = 2 * pwg + p;
        if (lane < 4 && pw < 15) {
            int pixel = (n * 15 + ph) * 15 + pw;
            y3p[pixel * 4 + half * 2 + (lane & 1)] = val;
        }
    }
}

__global__ __launch_bounds__(256, 2) void bconv4(const uint4* __restrict__ y3p,
                                                 const uint32_t* __restrict__ w4p,
                                                 const float* __restrict__ m,
                                                 const float* __restrict__ v,
                                                 const float* __restrict__ b,
                                                 float* __restrict__ out) {
    __shared__ __align__(16) uint32_t tile[64];

    int pixel = blockIdx.x;
    int lane = threadIdx.x & 63;
    int co = (threadIdx.x >> 6) * 64 + lane;
    int pw = pixel % 7;
    int t = pixel / 7;
    int ph = t % 7;
    int n = t / 7;

    if (threadIdx.x < 64) {
        int tt = threadIdx.x;
        int r = tt >> 4, e = (tt >> 2) & 3, w = tt & 3;
        int gr = 2 * ph - 1 + r, gc = 2 * pw - 1 + e;
        uint32_t val = 0;
        if (gr >= 0 && gr < 15 && gc >= 0 && gc < 15)
            val = ((const uint32_t*)y3p)[(((size_t)(n * 15 + gr) * 15 + gc) << 2) + w];
        tile[tt] = val;
    }
    __syncthreads();

    const uint4* tp = (const uint4*)tile;

    uint4 wq[9];
#pragma unroll
    for (int tap = 0; tap < 9; tap++) {
        wq[tap].x = w4p[(tap * 4 + 0) * 256 + co];
        wq[tap].y = w4p[(tap * 4 + 1) * 256 + co];
        wq[tap].z = w4p[(tap * 4 + 2) * 256 + co];
        wq[tap].w = w4p[(tap * 4 + 3) * 256 + co];
    }

    int best;
    if (ph > 0 && pw > 0) {
        int a0 = 0, a1 = 0, a2 = 0, a3 = 0;
#pragma unroll
        for (int r = 0; r < 4; r++)
#pragma unroll
            for (int c = 0; c < 4; c++) {
                uint4 iv = tp[r * 4 + c];
#pragma unroll
                for (int kh = 0; kh < 3; kh++) {
                    int dy = r - kh;
                    if (dy < 0 || dy > 1) continue;
#pragma unroll
                    for (int kw = 0; kw < 3; kw++) {
                        int dx = c - kw;
                        if (dx < 0 || dx > 1) continue;
                        int tap = kh * 3 + kw;
                        int pc = __popc(iv.x ^ wq[tap].x) + __popc(iv.y ^ wq[tap].y)
                               + __popc(iv.z ^ wq[tap].z) + __popc(iv.w ^ wq[tap].w);
                        if (dy == 0 && dx == 0) a0 += pc;
                        else if (dy == 0) a1 += pc;
                        else if (dx == 0) a2 += pc;
                        else a3 += pc;
                    }
                }
            }
        best = max(max(1152 - 2 * a0, 1152 - 2 * a1), max(1152 - 2 * a2, 1152 - 2 * a3));
    } else {
        best = -1000000;
#pragma unroll
        for (int dy = 0; dy < 2; dy++)
#pragma unroll
            for (int dx = 0; dx < 2; dx++) {
                int oh = 2 * ph + dy, ow = 2 * pw + dx;
                int acc = 0, K = 0;
#pragma unroll
                for (int kh = 0; kh < 3; kh++) {
                    int ih = oh - 1 + kh;
                    if (ih < 0 || ih >= 15) continue;
#pragma unroll
                    for (int kw = 0; kw < 3; kw++) {
                        int iw = ow - 1 + kw;
                        if (iw < 0 || iw >= 15) continue;
                        uint4 iv = tp[(dy + kh) * 4 + (dx + kw)];
                        int tap = kh * 3 + kw;
                        acc += __popc(iv.x ^ wq[tap].x) + __popc(iv.y ^ wq[tap].y)
                             + __popc(iv.z ^ wq[tap].z) + __popc(iv.w ^ wq[tap].w);
                        K += 128;
                    }
                }
                best = max(best, K - 2 * acc);
            }
    }
    float y = ((float)best - m[co]) * rsqrtf(v[co] + BN_EPS) + b[co];
    out[pixel * 256 + co] = y;
}

extern "C" void kernel_launch(void* const* d_in, const int* in_sizes, int n_in,
                              void* d_out, int out_size, void* d_ws, size_t ws_size,
                              hipStream_t stream) {
    const float* x  = (const float*)d_in[0];
    const float* w1 = (const float*)d_in[1];
    const float* m1 = (const float*)d_in[2];
    const float* v1 = (const float*)d_in[3];
    const float* b1 = (const float*)d_in[4];
    const float* w2 = (const float*)d_in[5];
    const float* m2 = (const float*)d_in[6];
    const float* v2 = (const float*)d_in[7];
    const float* b2 = (const float*)d_in[8];
    const float* w3 = (const float*)d_in[9];
    const float* m3 = (const float*)d_in[10];
    const float* v3 = (const float*)d_in[11];
    const float* b3 = (const float*)d_in[12];
    const float* w4 = (const float*)d_in[13];
    const float* m4 = (const float*)d_in[14];
    const float* v4 = (const float*)d_in[15];
    const float* b4 = (const float*)d_in[16];
    float* out = (float*)d_out;

    char* ws = (char*)d_ws;
    size_t off = 0;
    auto take = [&](size_t bytes) -> char* {
        char* p = ws + off;
        off += (bytes + 255) & ~(size_t)255;
        return p;
    };
    uint32_t* y1p = (uint32_t*)take((size_t)64 * 63 * 63 * 4);
    uint2*    y2p = (uint2*)take((size_t)64 * 31 * 31 * 8);
    uint32_t* y3p = (uint32_t*)take((size_t)64 * 15 * 15 * 16);
    float*    w1s = (float*)take(864 * 4);
    uint32_t* w2p = (uint32_t*)take(576 * 4);
    uint32_t* w3p = (uint32_t*)take(2304 * 4);
    uint32_t* w4p = (uint32_t*)take(9216 * 4);

    FusedParams P;
    P.x = x; P.w1 = w1; P.m1 = m1; P.v1 = v1; P.b1 = b1;
    P.w2 = w2; P.m2 = m2; P.v2 = v2; P.b2 = b2;
    P.w3 = w3; P.m3 = m3; P.v3 = v3; P.b3 = b3;
    P.w4 = w4; P.m4 = m4; P.v4 = v4; P.b4 = b4;
    P.out = out;
    P.y1p = y1p; P.y2p = y2p; P.y3p = y3p;
    P.w1s = w1s; P.w2p = w2p; P.w3p = w3p; P.w4p = w4p;

    // One cooperative dispatch for the whole network. Grid sized by the
    // runtime occupancy query (256 CUs on MI355X), capped at 1024 blocks
    // (4/CU, guaranteed by __launch_bounds__(256,4) VGPR cap + 14.3 KB LDS).
    bool launched = false;
    int perMP = 0;
    hipError_t qe = hipOccupancyMaxActiveBlocksPerMultiprocessor(
        &perMP, (const void*)fused_all, 256, 0);
    if (qe == hipSuccess && perMP >= 1) {
        int gridn = perMP * 256;
        if (gridn > 1024) gridn = 1024;
        void* args[] = { (void*)&P };
        hipError_t le = hipLaunchCooperativeKernel((const void*)fused_all,
                                                   dim3(gridn), dim3(256),
                                                   args, 0, stream);
        launched = (le == hipSuccess);
    }

    if (!launched) {
        // fallback: verified 5-kernel pipeline
        pack_all<<<(864 + 576 + 2304 + 9216 + 255) / 256, 256, 0, stream>>>(
            w1, w2, w3, w4, w1s, w2p, w3p, w4p);
        conv1_k<<<64 * 16, 256, 0, stream>>>(x, w1s, m1, v1, b1, y1p);
        bconv2<<<64 * 31, 256, 0, stream>>>(y1p, w2p, m2, v2, b2, y2p);
        bconv3<<<64 * 15, 256, 0, stream>>>(y2p, w3p, m3, v3, b3, y3p);
        bconv4<<<64 * 7 * 7, 256, 0, stream>>>((const uint4*)y3p, w4p, m4, v4, b4, out);
    }
}

// Round 7
// 195.420 us; speedup vs baseline: 2.3084x; 2.3084x over previous
//
#include <hip/hip_runtime.h>
#include <stdint.h>

#define BN_EPS 1e-3f

// ============================================================
// Weight prep:
//  - w1s[864]: sign floats, w1s[tap*32+c] = (w1<0 ? -1.f : 1.f)
//  - w2p/w3p/w4p: bit-packed signs, bit=1 <=> w<0, layout [(tap*CINW+wi)][COUT]
// ============================================================
template <int CIN, int COUT>
__device__ inline void packw(const float* __restrict__ w, uint32_t* __restrict__ wp, int idx) {
    const int CINW = CIN / 32;
    int co = idx % COUT;
    int t2 = idx / COUT;
    int wi = t2 % CINW;
    int tap = t2 / CINW;
    uint32_t word = 0;
#pragma unroll
    for (int bb = 0; bb < 32; bb++) {
        float val = w[((tap * CIN) + wi * 32 + bb) * COUT + co];
        word |= (uint32_t)(val < 0.f) << bb;
    }
    wp[idx] = word;
}

__global__ void pack_all(const float* __restrict__ w1, const float* __restrict__ w2,
                         const float* __restrict__ w3, const float* __restrict__ w4,
                         float* __restrict__ w1s, uint32_t* __restrict__ w2p,
                         uint32_t* __restrict__ w3p, uint32_t* __restrict__ w4p) {
    int idx = blockIdx.x * 256 + threadIdx.x;
    if (idx < 864) {
        w1s[idx] = (w1[idx] < 0.f) ? -1.f : 1.f;
        return;
    }
    idx -= 864;
    if (idx < 576) { packw<32, 64>(w2, w2p, idx); return; }
    idx -= 576;
    if (idx < 2304) { packw<64, 128>(w3, w3p, idx); return; }
    idx -= 2304;
    if (idx < 9216) { packw<128, 256>(w4, w4p, idx); return; }
}

// ============================================================
// Layer 1: conv(x, sign(w1), VALID) + maxpool2 + bn + sign -> packed u32.
// (R1 version verbatim -- best measured 44 us; control kernel)
// ============================================================
__global__ __launch_bounds__(256, 4) void conv1_k(const float* __restrict__ x,
                                                  const float* __restrict__ w1s,
                                                  const float* __restrict__ m1,
                                                  const float* __restrict__ v1,
                                                  const float* __restrict__ b1,
                                                  uint32_t* __restrict__ y1p) {
    __shared__ __align__(16) float xt[34 * 104];

    int tile = blockIdx.x;
    int tx = tile & 3;
    int ty = (tile >> 2) & 3;
    int n  = tile >> 4;
    int ph0 = ty * 16, pw0 = tx * 16;
    int r0 = 2 * ph0;
    int cf0 = pw0 * 6;

    for (int i = threadIdx.x; i < 34 * 102; i += 256) {
        int r = i / 102, c = i % 102;
        int gr = r0 + r, gcf = cf0 + c;
        float vv = 0.f;
        if (gr < 128 && gcf < 384)
            vv = x[(size_t)(n * 128 + gr) * 384 + gcf];
        xt[r * 104 + c] = vv;
    }
    __syncthreads();

    int wave = threadIdx.x >> 6, lane = threadIdx.x & 63;
    int px = lane & 15, py = (wave << 2) + (lane >> 4);
    int ph = ph0 + py, pw = pw0 + px;

    float win[48];
#pragma unroll
    for (int r = 0; r < 4; r++) {
        const float2* bp = (const float2*)&xt[(2 * py + r) * 104 + 6 * px];
#pragma unroll
        for (int q = 0; q < 6; q++) {
            float2 f2 = bp[q];
            win[r * 12 + 2 * q]     = f2.x;
            win[r * 12 + 2 * q + 1] = f2.y;
        }
    }

    uint32_t word = 0;
#pragma unroll 1
    for (int g = 0; g < 4; g++) {
        float acc[8][4];
#pragma unroll
        for (int j = 0; j < 8; j++)
#pragma unroll
            for (int p = 0; p < 4; p++) acc[j][p] = 0.f;

        const float* sgc = w1s + g * 8;
#pragma unroll
        for (int kh = 0; kh < 3; kh++)
#pragma unroll
            for (int kw = 0; kw < 3; kw++)
#pragma unroll
                for (int ci = 0; ci < 3; ci++) {
                    int tap = (kh * 3 + kw) * 3 + ci;
                    float x00 = win[kh * 12 + kw * 3 + ci];
                    float x01 = win[kh * 12 + (kw + 1) * 3 + ci];
                    float x10 = win[(kh + 1) * 12 + kw * 3 + ci];
                    float x11 = win[(kh + 1) * 12 + (kw + 1) * 3 + ci];
                    float4 s0 = *(const float4*)(sgc + tap * 32);
                    float4 s1 = *(const float4*)(sgc + tap * 32 + 4);
                    float sv[8] = {s0.x, s0.y, s0.z, s0.w, s1.x, s1.y, s1.z, s1.w};
#pragma unroll
                    for (int j = 0; j < 8; j++) {
                        acc[j][0] += x00 * sv[j];
                        acc[j][1] += x01 * sv[j];
                        acc[j][2] += x10 * sv[j];
                        acc[j][3] += x11 * sv[j];
                    }
                }
#pragma unroll
        for (int j = 0; j < 8; j++) {
            float mx = fmaxf(fmaxf(acc[j][0], acc[j][1]), fmaxf(acc[j][2], acc[j][3]));
            int ch = g * 8 + j;
            float y = (mx - m1[ch]) * rsqrtf(v1[ch] + BN_EPS) + b1[ch];
            word |= (uint32_t)(y < 0.f) << ch;
        }
    }

    if (ph < 63 && pw < 63)
        y1p[(n * 63 + ph) * 63 + pw] = word;
}

// ============================================================
// Layer 2: bconv(SAME, 63x63, CIN=32) + maxpool2 + bn + sign -> packed
// CODE-SIZE SHRUNK: single general path (the verified R5 edge-path
// arithmetic) for ALL pixels; pixel loop and 2x2 subwindow loop ROLLED
// (#pragma unroll 1); only the 9-tap loop stays unrolled so wq[] remains
// register-resident. Body ~2 KB instead of ~20 KB (I$-resident).
// Integer popc sums are order-exact; interior pixels get K=288 and the
// same max over 4 candidates as the old fast path -> bit-identical.
// ============================================================
__global__ __launch_bounds__(256) void bconv2(const uint32_t* __restrict__ y1p,
                                              const uint32_t* __restrict__ w2p,
                                              const float* __restrict__ m,
                                              const float* __restrict__ v,
                                              const float* __restrict__ b,
                                              uint2* __restrict__ y2p) {
    __shared__ uint32_t tile[4 * 64];    // 4 rows x 63 words (pad 64)

    int blk = blockIdx.x;
    int ph = blk % 31;
    int n  = blk / 31;
    int lane = threadIdx.x & 63;
    int wave = threadIdx.x >> 6;

    int row0 = 2 * ph - 1;               // may be -1 for ph=0 (clamped rows unused)
    for (int i = threadIdx.x; i < 4 * 63; i += 256) {
        int r = i / 63, c = i % 63;
        int rr = min(max(row0 + r, 0), 62);
        tile[r * 64 + c] = y1p[(n * 63 + rr) * 63 + c];
    }
    __syncthreads();

    uint32_t wq[9];
#pragma unroll
    for (int tap = 0; tap < 9; tap++) wq[tap] = w2p[tap * 64 + lane];
    float mm = m[lane];
    float rs = rsqrtf(v[lane] + BN_EPS);
    float bb = b[lane];

#pragma unroll 1
    for (int pw = wave; pw < 31; pw += 4) {
        int best = -1000000;
#pragma unroll 1
        for (int q = 0; q < 4; q++) {
            int dy = q >> 1, dx = q & 1;
            int oh = 2 * ph + dy, ow = 2 * pw + dx;
            int acc = 0, K = 0;
#pragma unroll
            for (int kh = 0; kh < 3; kh++) {
                int ih = oh - 1 + kh;
                bool rok = (ih >= 0) && (ih < 63);
#pragma unroll
                for (int kw = 0; kw < 3; kw++) {
                    int iw = ow - 1 + kw;
                    bool ok = rok && (iw >= 0) && (iw < 63);
                    uint32_t wv = tile[(dy + kh) * 64 + min(max(iw, 0), 62)];
                    acc += ok ? __popc(wv ^ wq[kh * 3 + kw]) : 0;
                    K += ok ? 32 : 0;
                }
            }
            best = max(best, K - 2 * acc);
        }
        float y = ((float)best - mm) * rs + bb;
        unsigned long long bal = __ballot(y < 0.f);
        if (lane == 0)
            y2p[(n * 31 + ph) * 31 + pw] = make_uint2((uint32_t)bal, (uint32_t)(bal >> 32));
    }
}

// ============================================================
// Layer 3: bconv(SAME, 31x31, CIN=64) + maxpool2 + bn + sign -> packed
// Same shrink: general path only, rolled px + subwindow loops.
// wave&1 = co-half; pw = (wave>>1) + 2*i.
// ============================================================
__global__ __launch_bounds__(256) void bconv3(const uint2* __restrict__ y2p,
                                              const uint32_t* __restrict__ w3p,
                                              const float* __restrict__ m,
                                              const float* __restrict__ v,
                                              const float* __restrict__ b,
                                              uint32_t* __restrict__ y3p) {
    __shared__ uint2 tile[4 * 32];       // 4 rows x 31 uint2 (pad 32)

    int blk = blockIdx.x;
    int ph = blk % 15;
    int n  = blk / 15;
    int lane = threadIdx.x & 63;
    int wave = threadIdx.x >> 6;
    int half = wave & 1;
    int co = half * 64 + lane;

    int row0 = 2 * ph - 1;
    for (int i = threadIdx.x; i < 4 * 31; i += 256) {
        int r = i / 31, c = i % 31;
        int rr = min(max(row0 + r, 0), 30);
        tile[r * 32 + c] = y2p[(n * 31 + rr) * 31 + c];
    }
    __syncthreads();

    uint32_t wq0[9], wq1[9];
#pragma unroll
    for (int tap = 0; tap < 9; tap++) {
        wq0[tap] = w3p[(tap * 2 + 0) * 128 + co];
        wq1[tap] = w3p[(tap * 2 + 1) * 128 + co];
    }
    float mm = m[co];
    float rs = rsqrtf(v[co] + BN_EPS);
    float bb = b[co];

#pragma unroll 1
    for (int pw = (wave >> 1); pw < 15; pw += 2) {
        int best = -1000000;
#pragma unroll 1
        for (int q = 0; q < 4; q++) {
            int dy = q >> 1, dx = q & 1;
            int oh = 2 * ph + dy, ow = 2 * pw + dx;
            int acc = 0, K = 0;
#pragma unroll
            for (int kh = 0; kh < 3; kh++) {
                int ih = oh - 1 + kh;
                bool rok = (ih >= 0) && (ih < 31);
#pragma unroll
                for (int kw = 0; kw < 3; kw++) {
                    int iw = ow - 1 + kw;
                    bool ok = rok && (iw >= 0) && (iw < 31);
                    uint2 iv = tile[(dy + kh) * 32 + min(max(iw, 0), 30)];
                    int tap = kh * 3 + kw;
                    acc += ok ? (__popc(iv.x ^ wq0[tap]) + __popc(iv.y ^ wq1[tap])) : 0;
                    K += ok ? 64 : 0;
                }
            }
            best = max(best, K - 2 * acc);
        }
        float y = ((float)best - mm) * rs + bb;
        unsigned long long bal = __ballot(y < 0.f);
        uint32_t val = (lane & 1) ? (uint32_t)(bal >> 32) : (uint32_t)bal;
        if (lane < 2) {
            int pixel = (n * 15 + ph) * 15 + pw;
            y3p[pixel * 4 + half * 2 + lane] = val;
        }
    }
}

// ============================================================
// Layer 4: bconv(SAME, 15x15, CIN=128) + maxpool2 + bn -> f32 out
// Same shrink: general path only (verified R5 edge arithmetic), rolled
// subwindow loop. Block per pixel; co = wave*64+lane.
// ============================================================
__global__ __launch_bounds__(256) void bconv4(const uint4* __restrict__ y3p,
                                              const uint32_t* __restrict__ w4p,
                                              const float* __restrict__ m,
                                              const float* __restrict__ v,
                                              const float* __restrict__ b,
                                              float* __restrict__ out) {
    __shared__ __align__(16) uint32_t tile[64];   // 4x4 window of uint4

    int pixel = blockIdx.x;
    int lane = threadIdx.x & 63;
    int co = (threadIdx.x >> 6) * 64 + lane;
    int pw = pixel % 7;
    int t = pixel / 7;
    int ph = t % 7;
    int n = t / 7;

    if (threadIdx.x < 64) {
        int tt = threadIdx.x;
        int r = tt >> 4, e = (tt >> 2) & 3, w = tt & 3;
        int gr = 2 * ph - 1 + r, gc = 2 * pw - 1 + e;
        uint32_t val = 0;
        if (gr >= 0 && gr < 15 && gc >= 0 && gc < 15)
            val = ((const uint32_t*)y3p)[(((size_t)(n * 15 + gr) * 15 + gc) << 2) + w];
        tile[tt] = val;
    }
    __syncthreads();

    const uint4* tp = (const uint4*)tile;

    uint4 wq[9];
#pragma unroll
    for (int tap = 0; tap < 9; tap++) {
        wq[tap].x = w4p[(tap * 4 + 0) * 256 + co];
        wq[tap].y = w4p[(tap * 4 + 1) * 256 + co];
        wq[tap].z = w4p[(tap * 4 + 2) * 256 + co];
        wq[tap].w = w4p[(tap * 4 + 3) * 256 + co];
    }

    int best = -1000000;
#pragma unroll 1
    for (int q = 0; q < 4; q++) {
        int dy = q >> 1, dx = q & 1;
        int oh = 2 * ph + dy, ow = 2 * pw + dx;
        int acc = 0, K = 0;
#pragma unroll
        for (int kh = 0; kh < 3; kh++) {
            int ih = oh - 1 + kh;
            bool rok = (ih >= 0) && (ih < 15);
#pragma unroll
            for (int kw = 0; kw < 3; kw++) {
                int iw = ow - 1 + kw;
                bool ok = rok && (iw >= 0) && (iw < 15);
                // tile row = ih-(2ph-1) = dy+kh, col = dx+kw (always in [0,3])
                uint4 iv = tp[(dy + kh) * 4 + (dx + kw)];
                int tap = kh * 3 + kw;
                int pc = __popc(iv.x ^ wq[tap].x) + __popc(iv.y ^ wq[tap].y)
                       + __popc(iv.z ^ wq[tap].z) + __popc(iv.w ^ wq[tap].w);
                acc += ok ? pc : 0;
                K += ok ? 128 : 0;
            }
        }
        best = max(best, K - 2 * acc);
    }
    float y = ((float)best - m[co]) * rsqrtf(v[co] + BN_EPS) + b[co];
    out[pixel * 256 + co] = y;
}

extern "C" void kernel_launch(void* const* d_in, const int* in_sizes, int n_in,
                              void* d_out, int out_size, void* d_ws, size_t ws_size,
                              hipStream_t stream) {
    const float* x  = (const float*)d_in[0];
    const float* w1 = (const float*)d_in[1];
    const float* m1 = (const float*)d_in[2];
    const float* v1 = (const float*)d_in[3];
    const float* b1 = (const float*)d_in[4];
    const float* w2 = (const float*)d_in[5];
    const float* m2 = (const float*)d_in[6];
    const float* v2 = (const float*)d_in[7];
    const float* b2 = (const float*)d_in[8];
    const float* w3 = (const float*)d_in[9];
    const float* m3 = (const float*)d_in[10];
    const float* v3 = (const float*)d_in[11];
    const float* b3 = (const float*)d_in[12];
    const float* w4 = (const float*)d_in[13];
    const float* m4 = (const float*)d_in[14];
    const float* v4 = (const float*)d_in[15];
    const float* b4 = (const float*)d_in[16];
    float* out = (float*)d_out;

    char* ws = (char*)d_ws;
    size_t off = 0;
    auto take = [&](size_t bytes) -> char* {
        char* p = ws + off;
        off += (bytes + 255) & ~(size_t)255;
        return p;
    };
    uint32_t* y1p = (uint32_t*)take((size_t)64 * 63 * 63 * 4);
    uint2*    y2p = (uint2*)take((size_t)64 * 31 * 31 * 8);
    uint32_t* y3p = (uint32_t*)take((size_t)64 * 15 * 15 * 16);
    float*    w1s = (float*)take(864 * 4);
    uint32_t* w2p = (uint32_t*)take(576 * 4);
    uint32_t* w3p = (uint32_t*)take(2304 * 4);
    uint32_t* w4p = (uint32_t*)take(9216 * 4);

    pack_all<<<(864 + 576 + 2304 + 9216 + 255) / 256, 256, 0, stream>>>(
        w1, w2, w3, w4, w1s, w2p, w3p, w4p);

    conv1_k<<<64 * 16, 256, 0, stream>>>(x, w1s, m1, v1, b1, y1p);

    bconv2<<<64 * 31, 256, 0, stream>>>(y1p, w2p, m2, v2, b2, y2p);

    bconv3<<<64 * 15, 256, 0, stream>>>(y2p, w3p, m3, v3, b3, y3p);

    bconv4<<<64 * 7 * 7, 256, 0, stream>>>((const uint4*)y3p, w4p, m4, v4, b4, out);
}